// Round 12
// baseline (274.568 us; speedup 1.0000x reference)
//
#include <hip/hip_runtime.h>
#include <math.h>

#define EPSV 1e-5f

typedef __attribute__((ext_vector_type(8))) short short8;
typedef __attribute__((ext_vector_type(4))) float f32x4;

__device__ __forceinline__ unsigned short f2b(float f) {
  union { float f; unsigned int u; } c; c.f = f;
  unsigned int u = c.u + 0x7fffu + ((c.u >> 16) & 1u);
  return (unsigned short)(u >> 16);
}
__device__ __forceinline__ float b2f(unsigned short h) {
  union { unsigned int u; float f; } c; c.u = ((unsigned int)h) << 16;
  return c.f;
}
__device__ __forceinline__ float ub(unsigned int w, int j) {  // byte j of dword -> float
  return (float)((w >> (8 * j)) & 0xffu);
}

// ---------------------------------------------------------------- weight prep (all layers)
// also zeroes cntI/cursor (folded memsets)
__global__ void k_prep_all(const float* __restrict__ Wl1, const float* __restrict__ Wr1,
                           const float* __restrict__ Wl2, const float* __restrict__ Wr2,
                           const float* __restrict__ Wg,
                           unsigned short* __restrict__ WlT1, unsigned short* __restrict__ WrT1,
                           unsigned short* __restrict__ WlT2, unsigned short* __restrict__ WrT2,
                           unsigned short* __restrict__ WgT,
                           int* __restrict__ cntI, int* __restrict__ cursor, int nN) {
  int id = blockIdx.x * 256 + threadIdx.x;  // 0..98303
  if (id < nN) { cntI[id] = 0; cursor[id] = 0; }
  if (id < 16384) {
    int n = id >> 7, k = id & 127;
    WlT1[id] = f2b(Wl1[k * 128 + n]);
  } else if (id < 32768) {
    int j = id - 16384; int n = j >> 7, k = j & 127;
    WrT1[j] = f2b(Wr1[k * 128 + n]);
  } else if (id < 49152) {
    int j = id - 32768; int n = j >> 7, k = j & 127;
    WlT2[j] = f2b(Wl2[k * 128 + n]);
  } else if (id < 65536) {
    int j = id - 49152; int n = j >> 7, k = j & 127;
    WrT2[j] = f2b(Wr2[k * 128 + n]);
  } else if (id < 98304) {
    int j = id - 65536; int n = j >> 7, k = j & 127;
    WgT[j] = f2b(Wg[k * 256 + n]);
  }
}

// ---------------------------------------------------------------- input proj
// 64 lanes/node, 2 feats/lane; writes bf16 + uint8(rowquant) + meta
__global__ void k_proj(const float* __restrict__ x, const float* __restrict__ W,
                       const float* __restrict__ b, unsigned short* __restrict__ h16,
                       unsigned char* __restrict__ h8, float2* __restrict__ hmeta, int nN) {
  int t = blockIdx.x * 256 + threadIdx.x;
  int n = t >> 6;
  if (n >= nN) return;
  int lane = t & 63;
  const float* xr = x + (size_t)n * 14;
  float acc0 = b[lane], acc1 = b[lane + 64];
#pragma unroll
  for (int k = 0; k < 14; ++k) {
    float xv = xr[k];
    acc0 = fmaf(xv, W[k * 128 + lane], acc0);
    acc1 = fmaf(xv, W[k * 128 + lane + 64], acc1);
  }
  float o0 = fmaxf(acc0, 0.f), o1 = fmaxf(acc1, 0.f);
  h16[(size_t)n * 128 + lane] = f2b(o0);
  h16[(size_t)n * 128 + lane + 64] = f2b(o1);
  float rmin = fminf(o0, o1), rmax = fmaxf(o0, o1);
#pragma unroll
  for (int m = 1; m <= 32; m <<= 1) {
    rmin = fminf(rmin, __shfl_xor(rmin, m));
    rmax = fmaxf(rmax, __shfl_xor(rmax, m));
  }
  float scale = (rmax - rmin) * (1.f / 255.f);
  float invq = (rmax > rmin) ? 255.f / (rmax - rmin) : 0.f;
  h8[(size_t)n * 128 + lane] = (unsigned char)(int)rintf((o0 - rmin) * invq);
  h8[(size_t)n * 128 + lane + 64] = (unsigned char)(int)rintf((o1 - rmin) * invq);
  if (lane == 0) hmeta[n] = make_float2(scale, rmin);
}

// ---------------------------------------------------------------- degree count
__global__ void k_count_int(const int* __restrict__ dst, int* __restrict__ cnt, int E_) {
  int e = blockIdx.x * 256 + threadIdx.x;
  if (e < E_) atomicAdd(&cnt[dst[e]], 1);
}

// ---------------------------------------------------------------- scan (3-phase)
__global__ void k_scan1(const int* __restrict__ cnt, int* __restrict__ incl,
                        int* __restrict__ bsum, int nN) {
  __shared__ int sh[256];
  int tid = threadIdx.x;
  int i = blockIdx.x * 256 + tid;
  int v = (i < nN) ? cnt[i] : 0;
  sh[tid] = v;
  __syncthreads();
#pragma unroll
  for (int off = 1; off < 256; off <<= 1) {
    int t = (tid >= off) ? sh[tid - off] : 0;
    __syncthreads();
    sh[tid] += t;
    __syncthreads();
  }
  if (i < nN) incl[i] = sh[tid];
  if (tid == 255) bsum[blockIdx.x] = sh[255];
}

__global__ void k_scan2(int* __restrict__ bsum, int nb) {
  __shared__ int sh[256];
  int tid = threadIdx.x;
  int v = (tid < nb) ? bsum[tid] : 0;
  sh[tid] = v;
  __syncthreads();
#pragma unroll
  for (int off = 1; off < 256; off <<= 1) {
    int t = (tid >= off) ? sh[tid - off] : 0;
    __syncthreads();
    sh[tid] += t;
    __syncthreads();
  }
  if (tid < nb) bsum[tid] = sh[tid] - v;  // exclusive
}

__global__ void k_scan3(const int* __restrict__ incl, const int* __restrict__ bsum,
                        const int* __restrict__ cnt, int* __restrict__ rowptr, int nN) {
  int i = blockIdx.x * 256 + threadIdx.x;
  if (i < nN) rowptr[i] = incl[i] - cnt[i] + bsum[blockIdx.x];
}

// ---------------------------------------------------------------- CSR fill
__global__ void k_fill(const int* __restrict__ src, const int* __restrict__ dst,
                       const int* __restrict__ rowptr, int* __restrict__ cursor,
                       int* __restrict__ eSrc, int E_) {
  int e = blockIdx.x * 256 + threadIdx.x;
  if (e >= E_) return;
  int d = dst[e];
  int pos = rowptr[d] + atomicAdd(&cursor[d], 1);
  eSrc[pos] = src[e];
}

// ---------------------------------------------------------------- SAGE gather-mean (uint8)
// 64 lanes/NODE: 16 feat-lanes (8B uint8) x 4 edge-slots; 2 banks/slot (8 edges in flight)
__global__ void k_sage_gather8(const unsigned char* __restrict__ h8,
                               const float2* __restrict__ hmeta,
                               const int* __restrict__ rowptr, const int* __restrict__ cnt,
                               const int* __restrict__ eSrc,
                               unsigned short* __restrict__ agg16, int nN) {
  int t = blockIdx.x * 256 + threadIdx.x;
  int n = t >> 6;
  if (n >= nN) return;
  int lane = t & 63;
  int flane = lane & 15;
  int slot = lane >> 4;  // 0..3
  int fo = flane * 8;
  int beg = rowptr[n], c = cnt[n];
  float a0[8], a1[8];
#pragma unroll
  for (int j = 0; j < 8; ++j) { a0[j] = 0.f; a1[j] = 0.f; }
  float m0 = 0.f, m1 = 0.f;
  int i = slot;
  for (; i + 4 < c; i += 8) {  // edges i and i+4
    int s0 = eSrc[beg + i], s1 = eSrc[beg + i + 4];
    float2 t0 = hmeta[s0], t1 = hmeta[s1];
    uint2 p0 = *(const uint2*)(h8 + (size_t)s0 * 128 + fo);
    uint2 p1 = *(const uint2*)(h8 + (size_t)s1 * 128 + fo);
#pragma unroll
    for (int j = 0; j < 4; ++j) {
      a0[j] = fmaf(t0.x, ub(p0.x, j), a0[j]);
      a1[j] = fmaf(t1.x, ub(p1.x, j), a1[j]);
      a0[j + 4] = fmaf(t0.x, ub(p0.y, j), a0[j + 4]);
      a1[j + 4] = fmaf(t1.x, ub(p1.y, j), a1[j + 4]);
    }
    m0 += t0.y; m1 += t1.y;
  }
  for (; i < c; i += 4) {
    int s = eSrc[beg + i];
    float2 tm = hmeta[s];
    uint2 p = *(const uint2*)(h8 + (size_t)s * 128 + fo);
#pragma unroll
    for (int j = 0; j < 4; ++j) {
      a0[j] = fmaf(tm.x, ub(p.x, j), a0[j]);
      a0[j + 4] = fmaf(tm.x, ub(p.y, j), a0[j + 4]);
    }
    m0 += tm.y;
  }
  float a[8];
  float mm = m0 + m1;
#pragma unroll
  for (int j = 0; j < 8; ++j) a[j] = a0[j] + a1[j];
  // merge 4 edge-slots (lane bits 4,5)
#pragma unroll
  for (int j = 0; j < 8; ++j) {
    a[j] += __shfl_xor(a[j], 16);
    a[j] += __shfl_xor(a[j], 32);
  }
  mm += __shfl_xor(mm, 16);
  mm += __shfl_xor(mm, 32);
  if (slot == 0) {
    float inv = 1.f / fmaxf((float)c, 1.f);
    short8 r;
#pragma unroll
    for (int j = 0; j < 8; ++j) r[j] = (short)f2b((a[j] + mm) * inv);
    *(short8*)(agg16 + (size_t)n * 128 + fo) = r;
  }
}

// ---------------------------------------------------------------- SAGE MFMA layer
__global__ __launch_bounds__(256)
void k_sage_mfma(const unsigned short* __restrict__ agg16,
                 const unsigned short* __restrict__ hin16,
                 const unsigned short* __restrict__ WlT,
                 const unsigned short* __restrict__ WrT,
                 const float* __restrict__ bias, const float* __restrict__ gam,
                 const float* __restrict__ bet,
                 unsigned short* __restrict__ hout16,
                 unsigned char* __restrict__ hout8, float2* __restrict__ hmeta_o,
                 int quant, int nN) {
  __shared__ unsigned short lA[64][136];
  __shared__ unsigned short lB[128][136];
  int tid = threadIdx.x;
  int wave = tid >> 6, lane = tid & 63;
  int cl = lane & 15, g = lane >> 4;
  int rowBase = blockIdx.x * 64;
  f32x4 acc[8];
#pragma unroll
  for (int ct = 0; ct < 8; ++ct) acc[ct] = (f32x4){0.f, 0.f, 0.f, 0.f};

  int ar = tid >> 2, ap = (tid & 3) * 32;
  int br = tid >> 1, bp = (tid & 1) * 64;

  for (int half = 0; half < 2; ++half) {
    const unsigned short* At = half ? hin16 : agg16;
    const unsigned short* Bt = half ? WrT : WlT;
    if (half) __syncthreads();
    {
      int grow = rowBase + ar;
      if (grow < nN) {
        const unsigned short* sp = At + (size_t)grow * 128 + ap;
#pragma unroll
        for (int u = 0; u < 4; ++u)
          *(short8*)&lA[ar][ap + u * 8] = *(const short8*)(sp + u * 8);
      } else {
        short8 z = {0, 0, 0, 0, 0, 0, 0, 0};
#pragma unroll
        for (int u = 0; u < 4; ++u) *(short8*)&lA[ar][ap + u * 8] = z;
      }
      const unsigned short* bsp = Bt + (size_t)br * 128 + bp;
#pragma unroll
      for (int u = 0; u < 8; ++u)
        *(short8*)&lB[br][bp + u * 8] = *(const short8*)(bsp + u * 8);
    }
    __syncthreads();
#pragma unroll
    for (int ks = 0; ks < 4; ++ks) {
      short8 a = *(const short8*)&lA[wave * 16 + cl][ks * 32 + g * 8];
#pragma unroll
      for (int ct = 0; ct < 8; ++ct) {
        short8 b = *(const short8*)&lB[ct * 16 + cl][ks * 32 + g * 8];
        acc[ct] = __builtin_amdgcn_mfma_f32_16x16x32_bf16(a, b, acc[ct], 0, 0, 0);
      }
    }
  }
  __syncthreads();

  float bcol[8], gcol[8], ecol[8];
#pragma unroll
  for (int ct = 0; ct < 8; ++ct) {
    int c = ct * 16 + cl;
    bcol[ct] = bias[c]; gcol[ct] = gam[c]; ecol[ct] = bet[c];
  }
  float v[8][4];
  float s1[4] = {0.f, 0.f, 0.f, 0.f}, s2[4] = {0.f, 0.f, 0.f, 0.f};
#pragma unroll
  for (int ct = 0; ct < 8; ++ct)
#pragma unroll
    for (int r = 0; r < 4; ++r) {
      float t = acc[ct][r] + bcol[ct];
      v[ct][r] = t;
      s1[r] += t; s2[r] += t * t;
    }
#pragma unroll
  for (int m = 1; m <= 8; m <<= 1)
#pragma unroll
    for (int r = 0; r < 4; ++r) { s1[r] += __shfl_xor(s1[r], m); s2[r] += __shfl_xor(s2[r], m); }

#pragma unroll
  for (int r = 0; r < 4; ++r) {
    float mean = s1[r] * (1.f / 128.f);
    float var = s2[r] * (1.f / 128.f) - mean * mean;
    float rstd = rsqrtf(var + EPSV);
    int grow = rowBase + wave * 16 + g * 4 + r;
    if (grow < nN) {
      float o8v[8];
      float rmin = 1e30f, rmax = -1e30f;
#pragma unroll
      for (int ct = 0; ct < 8; ++ct) {
        int c = ct * 16 + cl;
        float o = fmaxf((v[ct][r] - mean) * rstd * gcol[ct] + ecol[ct], 0.f)
                  + b2f(hin16[(size_t)grow * 128 + c]);
        o8v[ct] = o;
        rmin = fminf(rmin, o); rmax = fmaxf(rmax, o);
        hout16[(size_t)grow * 128 + c] = f2b(o);
      }
      if (quant) {
#pragma unroll
        for (int m = 1; m <= 8; m <<= 1) {
          rmin = fminf(rmin, __shfl_xor(rmin, m));
          rmax = fmaxf(rmax, __shfl_xor(rmax, m));
        }
        float scale = (rmax - rmin) * (1.f / 255.f);
        float invq = (rmax > rmin) ? 255.f / (rmax - rmin) : 0.f;
#pragma unroll
        for (int ct = 0; ct < 8; ++ct) {
          int c = ct * 16 + cl;
          hout8[(size_t)grow * 128 + c] = (unsigned char)(int)rintf((o8v[ct] - rmin) * invq);
        }
        if (cl == 0) hmeta_o[grow] = make_float2(scale, rmin);
      }
    }
  }
}

// ---------------------------------------------------------------- GAT GEMM (MFMA) + logits
__global__ __launch_bounds__(256)
void k_gatgemm(const unsigned short* __restrict__ h16, const unsigned short* __restrict__ WgT,
               const float* __restrict__ atts, const float* __restrict__ attd,
               unsigned char* __restrict__ G8, float2* __restrict__ Gmeta,
               float* __restrict__ as_, float* __restrict__ ad_, int nN) {
  __shared__ unsigned short lA[64][136];
  __shared__ unsigned short lB[128][136];
  int tid = threadIdx.x;
  int wave = tid >> 6, lane = tid & 63;
  int cl = lane & 15, g = lane >> 4;
  int rowBase = blockIdx.x * 64;
  int y = blockIdx.y;
  f32x4 acc[8];
#pragma unroll
  for (int ct = 0; ct < 8; ++ct) acc[ct] = (f32x4){0.f, 0.f, 0.f, 0.f};

  int ar = tid >> 2, ap = (tid & 3) * 32;
  int br = tid >> 1, bp = (tid & 1) * 64;
  {
    int grow = rowBase + ar;
    if (grow < nN) {
      const unsigned short* sp = h16 + (size_t)grow * 128 + ap;
#pragma unroll
      for (int u = 0; u < 4; ++u)
        *(short8*)&lA[ar][ap + u * 8] = *(const short8*)(sp + u * 8);
    } else {
      short8 z = {0, 0, 0, 0, 0, 0, 0, 0};
#pragma unroll
      for (int u = 0; u < 4; ++u) *(short8*)&lA[ar][ap + u * 8] = z;
    }
    const unsigned short* bsp = WgT + (size_t)(y * 128 + br) * 128 + bp;
#pragma unroll
    for (int u = 0; u < 8; ++u)
      *(short8*)&lB[br][bp + u * 8] = *(const short8*)(bsp + u * 8);
  }
  __syncthreads();
#pragma unroll
  for (int ks = 0; ks < 4; ++ks) {
    short8 a = *(const short8*)&lA[wave * 16 + cl][ks * 32 + g * 8];
#pragma unroll
    for (int ct = 0; ct < 8; ++ct) {
      short8 b = *(const short8*)&lB[ct * 16 + cl][ks * 32 + g * 8];
      acc[ct] = __builtin_amdgcn_mfma_f32_16x16x32_bf16(a, b, acc[ct], 0, 0, 0);
    }
  }

  float atr[8], adr[8];
#pragma unroll
  for (int ct = 0; ct < 8; ++ct) {
    int h = y * 2 + (ct >> 2);
    int w = (ct & 3) * 16 + cl;
    atr[ct] = atts[h * 64 + w];
    adr[ct] = attd[h * 64 + w];
  }
  float ps[2][4], pd[2][4];
#pragma unroll
  for (int hh = 0; hh < 2; ++hh)
#pragma unroll
    for (int r = 0; r < 4; ++r) { ps[hh][r] = 0.f; pd[hh][r] = 0.f; }

#pragma unroll
  for (int r = 0; r < 4; ++r) {
    int grow = rowBase + wave * 16 + g * 4 + r;
    float rmin = 1e30f, rmax = -1e30f;
#pragma unroll
    for (int ct = 0; ct < 8; ++ct) {
      rmin = fminf(rmin, acc[ct][r]); rmax = fmaxf(rmax, acc[ct][r]);
    }
#pragma unroll
    for (int m = 1; m <= 8; m <<= 1) {
      rmin = fminf(rmin, __shfl_xor(rmin, m));
      rmax = fmaxf(rmax, __shfl_xor(rmax, m));
    }
    float scale = (rmax - rmin) * (1.f / 255.f);
    float invq = (rmax > rmin) ? 255.f / (rmax - rmin) : 0.f;
    if (grow < nN) {
      unsigned char* op = G8 + (size_t)grow * 256 + y * 128 + cl;
#pragma unroll
      for (int ct = 0; ct < 8; ++ct)
        op[ct * 16] = (unsigned char)(int)rintf((acc[ct][r] - rmin) * invq);
      if (cl == 0) Gmeta[grow * 2 + y] = make_float2(scale, rmin);
    }
#pragma unroll
    for (int ct = 0; ct < 8; ++ct) {
      ps[ct >> 2][r] = fmaf(acc[ct][r], atr[ct], ps[ct >> 2][r]);
      pd[ct >> 2][r] = fmaf(acc[ct][r], adr[ct], pd[ct >> 2][r]);
    }
  }
#pragma unroll
  for (int m = 1; m <= 8; m <<= 1)
#pragma unroll
    for (int hh = 0; hh < 2; ++hh)
#pragma unroll
      for (int r = 0; r < 4; ++r) {
        ps[hh][r] += __shfl_xor(ps[hh][r], m);
        pd[hh][r] += __shfl_xor(pd[hh][r], m);
      }
  if (cl == 0) {
#pragma unroll
    for (int r = 0; r < 4; ++r) {
      int grow = rowBase + wave * 16 + g * 4 + r;
      if (grow < nN) {
#pragma unroll
        for (int hh = 0; hh < 2; ++hh) {
          as_[grow * 4 + y * 2 + hh] = ps[hh][r];
          ad_[grow * 4 + y * 2 + hh] = pd[hh][r];
        }
      }
    }
  }
}

// ---------------------------------------------------------------- fused GAT gather + LN (uint8 G)
// 64 lanes/NODE: 32 payload-lanes x 2 edge-slots (lane bit 5); 4 banks/slot (8 edges in flight)
__global__ void k_gat(const unsigned char* __restrict__ G8, const float2* __restrict__ Gmeta,
                      const int* __restrict__ rowptr, const int* __restrict__ cnt,
                      const int* __restrict__ eSrc,
                      const float* __restrict__ as_, const float* __restrict__ ad_,
                      const float* __restrict__ bg, const float* __restrict__ g3,
                      const float* __restrict__ be3, float* __restrict__ out, int nN) {
  int t = blockIdx.x * 256 + threadIdx.x;
  int n = t >> 6;
  if (n >= nN) return;
  int lane = t & 63;
  int sub = lane & 31;
  int slot = lane >> 5;  // 0/1
  int h = sub >> 3;
  int yy = sub >> 4;
  int fo = sub * 8;
  float adn = ad_[n * 4 + h];

  float a0[8], a1[8], a2[8], a3[8];
#pragma unroll
  for (int j = 0; j < 8; ++j) { a0[j] = 0.f; a1[j] = 0.f; a2[j] = 0.f; a3[j] = 0.f; }
  float m0 = 0.f, m1 = 0.f, m2 = 0.f, m3 = 0.f;
  float d0 = 0.f, d1 = 0.f, d2 = 0.f, d3 = 0.f;

  if (slot == 0) {  // self loop -> bank 0 of slot 0
    float e0 = as_[n * 4 + h] + adn;
    e0 = fmaxf(e0, 0.2f * e0);
    float w = __expf(e0);
    float2 mts = Gmeta[n * 2 + yy];
    uint2 p = *(const uint2*)(G8 + (size_t)n * 256 + fo);
    float ws = w * mts.x;
#pragma unroll
    for (int j = 0; j < 4; ++j) {
      a0[j] = ws * ub(p.x, j);
      a0[j + 4] = ws * ub(p.y, j);
    }
    m0 = w * mts.y;
    d0 = w;
  }

  int beg = rowptr[n], c = cnt[n];
  int i = slot;
  for (; i + 6 < c; i += 8) {  // 4 edges/slot-iter: i, i+2, i+4, i+6
    int s0 = eSrc[beg + i], s1i = eSrc[beg + i + 2];
    int s2i = eSrc[beg + i + 4], s3i = eSrc[beg + i + 6];
    float ev0 = as_[s0 * 4 + h] + adn;
    float ev1 = as_[s1i * 4 + h] + adn;
    float ev2 = as_[s2i * 4 + h] + adn;
    float ev3 = as_[s3i * 4 + h] + adn;
    ev0 = fmaxf(ev0, 0.2f * ev0); ev1 = fmaxf(ev1, 0.2f * ev1);
    ev2 = fmaxf(ev2, 0.2f * ev2); ev3 = fmaxf(ev3, 0.2f * ev3);
    float w0 = __expf(ev0), w1 = __expf(ev1), w2 = __expf(ev2), w3 = __expf(ev3);
    float2 t0 = Gmeta[s0 * 2 + yy], t1 = Gmeta[s1i * 2 + yy];
    float2 t2 = Gmeta[s2i * 2 + yy], t3 = Gmeta[s3i * 2 + yy];
    uint2 p0 = *(const uint2*)(G8 + (size_t)s0 * 256 + fo);
    uint2 p1 = *(const uint2*)(G8 + (size_t)s1i * 256 + fo);
    uint2 p2 = *(const uint2*)(G8 + (size_t)s2i * 256 + fo);
    uint2 p3 = *(const uint2*)(G8 + (size_t)s3i * 256 + fo);
    float ws0 = w0 * t0.x, ws1 = w1 * t1.x, ws2 = w2 * t2.x, ws3 = w3 * t3.x;
#pragma unroll
    for (int j = 0; j < 4; ++j) {
      a0[j] = fmaf(ws0, ub(p0.x, j), a0[j]);
      a1[j] = fmaf(ws1, ub(p1.x, j), a1[j]);
      a2[j] = fmaf(ws2, ub(p2.x, j), a2[j]);
      a3[j] = fmaf(ws3, ub(p3.x, j), a3[j]);
      a0[j + 4] = fmaf(ws0, ub(p0.y, j), a0[j + 4]);
      a1[j + 4] = fmaf(ws1, ub(p1.y, j), a1[j + 4]);
      a2[j + 4] = fmaf(ws2, ub(p2.y, j), a2[j + 4]);
      a3[j + 4] = fmaf(ws3, ub(p3.y, j), a3[j + 4]);
    }
    m0 = fmaf(w0, t0.y, m0); m1 = fmaf(w1, t1.y, m1);
    m2 = fmaf(w2, t2.y, m2); m3 = fmaf(w3, t3.y, m3);
    d0 += w0; d1 += w1; d2 += w2; d3 += w3;
  }
  for (; i < c; i += 2) {
    int s = eSrc[beg + i];
    float ev = as_[s * 4 + h] + adn;
    ev = fmaxf(ev, 0.2f * ev);
    float w = __expf(ev);
    float2 tm = Gmeta[s * 2 + yy];
    uint2 p = *(const uint2*)(G8 + (size_t)s * 256 + fo);
    float wsx = w * tm.x;
#pragma unroll
    for (int j = 0; j < 4; ++j) {
      a0[j] = fmaf(wsx, ub(p.x, j), a0[j]);
      a0[j + 4] = fmaf(wsx, ub(p.y, j), a0[j + 4]);
    }
    m0 = fmaf(w, tm.y, m0);
    d0 += w;
  }

  float den = (d0 + d1) + (d2 + d3);
  float mm = (m0 + m1) + (m2 + m3);
  float a[8];
#pragma unroll
  for (int j = 0; j < 8; ++j) a[j] = (a0[j] + a1[j]) + (a2[j] + a3[j]);
  // merge the two edge-slots (lane bit 5)
#pragma unroll
  for (int j = 0; j < 8; ++j) a[j] += __shfl_xor(a[j], 32);
  den += __shfl_xor(den, 32);
  mm += __shfl_xor(mm, 32);

  float inv = 1.f / den;
#pragma unroll
  for (int j = 0; j < 8; ++j) a[j] = (a[j] + mm) * inv;

  // head-mean over lane bits 3,4
#pragma unroll
  for (int j = 0; j < 8; ++j) {
    a[j] += __shfl_xor(a[j], 8);
    a[j] += __shfl_xor(a[j], 16);
  }
  int fb = (sub & 7) * 8;
  float v[8];
  float s1 = 0.f, s2 = 0.f;
#pragma unroll
  for (int j = 0; j < 8; ++j) {
    v[j] = a[j] * 0.25f + bg[fb + j];
    s1 += v[j]; s2 += v[j] * v[j];
  }
  // LN over 64 feats: reduce across lane bits 0-2
#pragma unroll
  for (int m = 1; m <= 4; m <<= 1) { s1 += __shfl_xor(s1, m); s2 += __shfl_xor(s2, m); }
  float mean = s1 * (1.f / 64.f);
  float var = s2 * (1.f / 64.f) - mean * mean;
  float rstd = rsqrtf(var + EPSV);
  if (lane < 8) {
    float* o = out + (size_t)n * 64 + fb;
    float4 o1, o2;
    o1.x = (v[0] - mean) * rstd * g3[fb + 0] + be3[fb + 0];
    o1.y = (v[1] - mean) * rstd * g3[fb + 1] + be3[fb + 1];
    o1.z = (v[2] - mean) * rstd * g3[fb + 2] + be3[fb + 2];
    o1.w = (v[3] - mean) * rstd * g3[fb + 3] + be3[fb + 3];
    o2.x = (v[4] - mean) * rstd * g3[fb + 4] + be3[fb + 4];
    o2.y = (v[5] - mean) * rstd * g3[fb + 5] + be3[fb + 5];
    o2.z = (v[6] - mean) * rstd * g3[fb + 6] + be3[fb + 6];
    o2.w = (v[7] - mean) * rstd * g3[fb + 7] + be3[fb + 7];
    *(float4*)o = o1;
    *(float4*)(o + 4) = o2;
  }
}

// ================================================================ launch
extern "C" void kernel_launch(void* const* d_in, const int* in_sizes, int n_in,
                              void* d_out, int out_size, void* d_ws, size_t ws_size,
                              hipStream_t stream) {
  const float* x    = (const float*)d_in[0];
  const int*   edge = (const int*)d_in[1];
  const float* W_in = (const float*)d_in[2];
  const float* b_in = (const float*)d_in[3];
  const float* W1_l = (const float*)d_in[4];
  const float* b1   = (const float*)d_in[5];
  const float* W1_r = (const float*)d_in[6];
  const float* g1   = (const float*)d_in[7];
  const float* be1  = (const float*)d_in[8];
  const float* W2_l = (const float*)d_in[9];
  const float* b2   = (const float*)d_in[10];
  const float* W2_r = (const float*)d_in[11];
  const float* g2   = (const float*)d_in[12];
  const float* be2  = (const float*)d_in[13];
  const float* W_g  = (const float*)d_in[14];
  const float* atts = (const float*)d_in[15];
  const float* attd = (const float*)d_in[16];
  const float* b_g  = (const float*)d_in[17];
  const float* g3   = (const float*)d_in[18];
  const float* be3  = (const float*)d_in[19];

  const int nN = in_sizes[0] / 14;
  const int E_ = in_sizes[1] / 2;
  const int* src = edge;
  const int* dst = edge + E_;

  char* W = (char*)d_ws;
  unsigned short* hA16  = (unsigned short*)W; W += (size_t)nN * 128 * 2;
  unsigned short* hB16  = (unsigned short*)W; W += (size_t)nN * 128 * 2;
  unsigned short* agg16 = (unsigned short*)W; W += (size_t)nN * 128 * 2;
  unsigned short* WlT1  = (unsigned short*)W; W += 16384 * 2;
  unsigned short* WrT1  = (unsigned short*)W; W += 16384 * 2;
  unsigned short* WlT2  = (unsigned short*)W; W += 16384 * 2;
  unsigned short* WrT2  = (unsigned short*)W; W += 16384 * 2;
  unsigned short* WgT   = (unsigned short*)W; W += 32768 * 2;
  float* AS_ = (float*)W;                W += (size_t)nN * 4 * 4;
  float* AD_ = (float*)W;                W += (size_t)nN * 4 * 4;
  float2* metaA = (float2*)W;            W += (size_t)nN * 8;
  float2* metaB = (float2*)W;            W += (size_t)nN * 8;
  float2* Gmeta = (float2*)W;            W += (size_t)nN * 2 * 8;
  int* cntI   = (int*)W;                 W += (size_t)nN * 4;
  int* rowptr = (int*)W;                 W += (size_t)nN * 4;
  int* cursor = (int*)W;                 W += (size_t)nN * 4;
  int* incl   = (int*)W;                 W += (size_t)nN * 4;
  int* bsum   = (int*)W;                 W += 1024 * 4;
  int* eSrc   = (int*)W;                 W += (size_t)E_ * 4;
  unsigned char* h8A = (unsigned char*)W; W += (size_t)nN * 128;
  unsigned char* h8B = (unsigned char*)W; W += (size_t)nN * 128;
  unsigned char* G8  = (unsigned char*)W; W += (size_t)nN * 256;

  const int SB = (nN + 255) / 256;  // 196 for N=50000 (must be <=256)
  const int NB = (nN + 63) / 64;

  // weight prep + zero cnt/cursor (independent of graph; all layers upfront)
  k_prep_all<<<384, 256, 0, stream>>>(W1_l, W1_r, W2_l, W2_r, W_g, WlT1, WrT1, WlT2, WrT2,
                                      WgT, cntI, cursor, nN);

  // CSR by dst
  k_count_int<<<(E_ + 255) / 256, 256, 0, stream>>>(dst, cntI, E_);
  k_scan1<<<SB, 256, 0, stream>>>(cntI, incl, bsum, nN);
  k_scan2<<<1, 256, 0, stream>>>(bsum, SB);
  k_scan3<<<SB, 256, 0, stream>>>(incl, bsum, cntI, rowptr, nN);
  k_fill<<<(E_ + 255) / 256, 256, 0, stream>>>(src, dst, rowptr, cursor, eSrc, E_);

  // input projection
  k_proj<<<(nN * 64 + 255) / 256, 256, 0, stream>>>(x, W_in, b_in, hA16, h8A, metaA, nN);

  // SAGE layer 1: hA -> hB
  k_sage_gather8<<<(nN * 64 + 255) / 256, 256, 0, stream>>>(h8A, metaA, rowptr, cntI, eSrc, agg16, nN);
  k_sage_mfma<<<NB, 256, 0, stream>>>(agg16, hA16, WlT1, WrT1, b1, g1, be1, hB16, h8B, metaB, 1, nN);

  // SAGE layer 2: hB -> hA
  k_sage_gather8<<<(nN * 64 + 255) / 256, 256, 0, stream>>>(h8B, metaB, rowptr, cntI, eSrc, agg16, nN);
  k_sage_mfma<<<NB, 256, 0, stream>>>(agg16, hB16, WlT2, WrT2, b2, g2, be2, hA16, h8A, metaA, 0, nN);

  // GAT: hA16 -> G8(+meta,+logits) -> out
  k_gatgemm<<<dim3(NB, 2), 256, 0, stream>>>(hA16, WgT, atts, attd, G8, Gmeta, AS_, AD_, nN);
  k_gat<<<(nN * 64 + 255) / 256, 256, 0, stream>>>(G8, Gmeta, rowptr, cntI, eSrc, AS_, AD_, b_g, g3, be3, (float*)d_out, nN);
}

// Round 13
// 257.191 us; speedup vs baseline: 1.0676x; 1.0676x over previous
//
#include <hip/hip_runtime.h>
#include <math.h>

#define EPSV 1e-5f

typedef __attribute__((ext_vector_type(8))) short short8;
typedef __attribute__((ext_vector_type(4))) float f32x4;

__device__ __forceinline__ unsigned short f2b(float f) {
  union { float f; unsigned int u; } c; c.f = f;
  unsigned int u = c.u + 0x7fffu + ((c.u >> 16) & 1u);
  return (unsigned short)(u >> 16);
}
__device__ __forceinline__ float b2f(unsigned short h) {
  union { unsigned int u; float f; } c; c.u = ((unsigned int)h) << 16;
  return c.f;
}
__device__ __forceinline__ float ub(unsigned int w, int j) {  // byte j of dword -> float
  return (float)((w >> (8 * j)) & 0xffu);
}

// ---------------------------------------------------------------- weight prep (all layers)
// also zeroes cntI/cursor (folded memsets)
__global__ void k_prep_all(const float* __restrict__ Wl1, const float* __restrict__ Wr1,
                           const float* __restrict__ Wl2, const float* __restrict__ Wr2,
                           const float* __restrict__ Wg,
                           unsigned short* __restrict__ WlT1, unsigned short* __restrict__ WrT1,
                           unsigned short* __restrict__ WlT2, unsigned short* __restrict__ WrT2,
                           unsigned short* __restrict__ WgT,
                           int* __restrict__ cntI, int* __restrict__ cursor, int nN) {
  int id = blockIdx.x * 256 + threadIdx.x;  // 0..98303
  if (id < nN) { cntI[id] = 0; cursor[id] = 0; }
  if (id < 16384) {
    int n = id >> 7, k = id & 127;
    WlT1[id] = f2b(Wl1[k * 128 + n]);
  } else if (id < 32768) {
    int j = id - 16384; int n = j >> 7, k = j & 127;
    WrT1[j] = f2b(Wr1[k * 128 + n]);
  } else if (id < 49152) {
    int j = id - 32768; int n = j >> 7, k = j & 127;
    WlT2[j] = f2b(Wl2[k * 128 + n]);
  } else if (id < 65536) {
    int j = id - 49152; int n = j >> 7, k = j & 127;
    WrT2[j] = f2b(Wr2[k * 128 + n]);
  } else if (id < 98304) {
    int j = id - 65536; int n = j >> 7, k = j & 127;
    WgT[j] = f2b(Wg[k * 256 + n]);
  }
}

// ---------------------------------------------------------------- input proj
// 64 lanes/node, 2 feats/lane; writes bf16 + uint8(rowquant) + meta
__global__ void k_proj(const float* __restrict__ x, const float* __restrict__ W,
                       const float* __restrict__ b, unsigned short* __restrict__ h16,
                       unsigned char* __restrict__ h8, float2* __restrict__ hmeta, int nN) {
  int t = blockIdx.x * 256 + threadIdx.x;
  int n = t >> 6;
  if (n >= nN) return;
  int lane = t & 63;
  const float* xr = x + (size_t)n * 14;
  float acc0 = b[lane], acc1 = b[lane + 64];
#pragma unroll
  for (int k = 0; k < 14; ++k) {
    float xv = xr[k];
    acc0 = fmaf(xv, W[k * 128 + lane], acc0);
    acc1 = fmaf(xv, W[k * 128 + lane + 64], acc1);
  }
  float o0 = fmaxf(acc0, 0.f), o1 = fmaxf(acc1, 0.f);
  h16[(size_t)n * 128 + lane] = f2b(o0);
  h16[(size_t)n * 128 + lane + 64] = f2b(o1);
  float rmin = fminf(o0, o1), rmax = fmaxf(o0, o1);
#pragma unroll
  for (int m = 1; m <= 32; m <<= 1) {
    rmin = fminf(rmin, __shfl_xor(rmin, m));
    rmax = fmaxf(rmax, __shfl_xor(rmax, m));
  }
  float scale = (rmax - rmin) * (1.f / 255.f);
  float invq = (rmax > rmin) ? 255.f / (rmax - rmin) : 0.f;
  h8[(size_t)n * 128 + lane] = (unsigned char)(int)rintf((o0 - rmin) * invq);
  h8[(size_t)n * 128 + lane + 64] = (unsigned char)(int)rintf((o1 - rmin) * invq);
  if (lane == 0) hmeta[n] = make_float2(scale, rmin);
}

// ---------------------------------------------------------------- degree count
__global__ void k_count_int(const int* __restrict__ dst, int* __restrict__ cnt, int E_) {
  int e = blockIdx.x * 256 + threadIdx.x;
  if (e < E_) atomicAdd(&cnt[dst[e]], 1);
}

// ---------------------------------------------------------------- scan (3-phase)
__global__ void k_scan1(const int* __restrict__ cnt, int* __restrict__ incl,
                        int* __restrict__ bsum, int nN) {
  __shared__ int sh[256];
  int tid = threadIdx.x;
  int i = blockIdx.x * 256 + tid;
  int v = (i < nN) ? cnt[i] : 0;
  sh[tid] = v;
  __syncthreads();
#pragma unroll
  for (int off = 1; off < 256; off <<= 1) {
    int t = (tid >= off) ? sh[tid - off] : 0;
    __syncthreads();
    sh[tid] += t;
    __syncthreads();
  }
  if (i < nN) incl[i] = sh[tid];
  if (tid == 255) bsum[blockIdx.x] = sh[255];
}

__global__ void k_scan2(int* __restrict__ bsum, int nb) {
  __shared__ int sh[256];
  int tid = threadIdx.x;
  int v = (tid < nb) ? bsum[tid] : 0;
  sh[tid] = v;
  __syncthreads();
#pragma unroll
  for (int off = 1; off < 256; off <<= 1) {
    int t = (tid >= off) ? sh[tid - off] : 0;
    __syncthreads();
    sh[tid] += t;
    __syncthreads();
  }
  if (tid < nb) bsum[tid] = sh[tid] - v;  // exclusive
}

__global__ void k_scan3(const int* __restrict__ incl, const int* __restrict__ bsum,
                        const int* __restrict__ cnt, int* __restrict__ rowptr, int nN) {
  int i = blockIdx.x * 256 + threadIdx.x;
  if (i < nN) rowptr[i] = incl[i] - cnt[i] + bsum[blockIdx.x];
}

// ---------------------------------------------------------------- CSR fill
__global__ void k_fill(const int* __restrict__ src, const int* __restrict__ dst,
                       const int* __restrict__ rowptr, int* __restrict__ cursor,
                       int* __restrict__ eSrc, int E_) {
  int e = blockIdx.x * 256 + threadIdx.x;
  if (e >= E_) return;
  int d = dst[e];
  int pos = rowptr[d] + atomicAdd(&cursor[d], 1);
  eSrc[pos] = src[e];
}

// ---------------------------------------------------------------- SAGE gather-mean (uint8)
// 64 lanes/NODE: 16 feat-lanes (8B uint8) x 4 edge-slots; 2 banks/slot (8 edges in flight)
__global__ void k_sage_gather8(const unsigned char* __restrict__ h8,
                               const float2* __restrict__ hmeta,
                               const int* __restrict__ rowptr, const int* __restrict__ cnt,
                               const int* __restrict__ eSrc,
                               unsigned short* __restrict__ agg16, int nN) {
  int t = blockIdx.x * 256 + threadIdx.x;
  int n = t >> 6;
  if (n >= nN) return;
  int lane = t & 63;
  int flane = lane & 15;
  int slot = lane >> 4;  // 0..3
  int fo = flane * 8;
  int beg = rowptr[n], c = cnt[n];
  float a0[8], a1[8];
#pragma unroll
  for (int j = 0; j < 8; ++j) { a0[j] = 0.f; a1[j] = 0.f; }
  float m0 = 0.f, m1 = 0.f;
  int i = slot;
  for (; i + 4 < c; i += 8) {  // edges i and i+4
    int s0 = eSrc[beg + i], s1 = eSrc[beg + i + 4];
    float2 t0 = hmeta[s0], t1 = hmeta[s1];
    uint2 p0 = *(const uint2*)(h8 + (size_t)s0 * 128 + fo);
    uint2 p1 = *(const uint2*)(h8 + (size_t)s1 * 128 + fo);
#pragma unroll
    for (int j = 0; j < 4; ++j) {
      a0[j] = fmaf(t0.x, ub(p0.x, j), a0[j]);
      a1[j] = fmaf(t1.x, ub(p1.x, j), a1[j]);
      a0[j + 4] = fmaf(t0.x, ub(p0.y, j), a0[j + 4]);
      a1[j + 4] = fmaf(t1.x, ub(p1.y, j), a1[j + 4]);
    }
    m0 += t0.y; m1 += t1.y;
  }
  for (; i < c; i += 4) {
    int s = eSrc[beg + i];
    float2 tm = hmeta[s];
    uint2 p = *(const uint2*)(h8 + (size_t)s * 128 + fo);
#pragma unroll
    for (int j = 0; j < 4; ++j) {
      a0[j] = fmaf(tm.x, ub(p.x, j), a0[j]);
      a0[j + 4] = fmaf(tm.x, ub(p.y, j), a0[j + 4]);
    }
    m0 += tm.y;
  }
  float a[8];
  float mm = m0 + m1;
#pragma unroll
  for (int j = 0; j < 8; ++j) a[j] = a0[j] + a1[j];
  // merge 4 edge-slots (lane bits 4,5)
#pragma unroll
  for (int j = 0; j < 8; ++j) {
    a[j] += __shfl_xor(a[j], 16);
    a[j] += __shfl_xor(a[j], 32);
  }
  mm += __shfl_xor(mm, 16);
  mm += __shfl_xor(mm, 32);
  if (slot == 0) {
    float inv = 1.f / fmaxf((float)c, 1.f);
    short8 r;
#pragma unroll
    for (int j = 0; j < 8; ++j) r[j] = (short)f2b((a[j] + mm) * inv);
    *(short8*)(agg16 + (size_t)n * 128 + fo) = r;
  }
}

// ---------------------------------------------------------------- SAGE MFMA layer
__global__ __launch_bounds__(256)
void k_sage_mfma(const unsigned short* __restrict__ agg16,
                 const unsigned short* __restrict__ hin16,
                 const unsigned short* __restrict__ WlT,
                 const unsigned short* __restrict__ WrT,
                 const float* __restrict__ bias, const float* __restrict__ gam,
                 const float* __restrict__ bet,
                 unsigned short* __restrict__ hout16,
                 unsigned char* __restrict__ hout8, float2* __restrict__ hmeta_o,
                 int quant, int nN) {
  __shared__ unsigned short lA[64][136];
  __shared__ unsigned short lB[128][136];
  int tid = threadIdx.x;
  int wave = tid >> 6, lane = tid & 63;
  int cl = lane & 15, g = lane >> 4;
  int rowBase = blockIdx.x * 64;
  f32x4 acc[8];
#pragma unroll
  for (int ct = 0; ct < 8; ++ct) acc[ct] = (f32x4){0.f, 0.f, 0.f, 0.f};

  int ar = tid >> 2, ap = (tid & 3) * 32;
  int br = tid >> 1, bp = (tid & 1) * 64;

  for (int half = 0; half < 2; ++half) {
    const unsigned short* At = half ? hin16 : agg16;
    const unsigned short* Bt = half ? WrT : WlT;
    if (half) __syncthreads();
    {
      int grow = rowBase + ar;
      if (grow < nN) {
        const unsigned short* sp = At + (size_t)grow * 128 + ap;
#pragma unroll
        for (int u = 0; u < 4; ++u)
          *(short8*)&lA[ar][ap + u * 8] = *(const short8*)(sp + u * 8);
      } else {
        short8 z = {0, 0, 0, 0, 0, 0, 0, 0};
#pragma unroll
        for (int u = 0; u < 4; ++u) *(short8*)&lA[ar][ap + u * 8] = z;
      }
      const unsigned short* bsp = Bt + (size_t)br * 128 + bp;
#pragma unroll
      for (int u = 0; u < 8; ++u)
        *(short8*)&lB[br][bp + u * 8] = *(const short8*)(bsp + u * 8);
    }
    __syncthreads();
#pragma unroll
    for (int ks = 0; ks < 4; ++ks) {
      short8 a = *(const short8*)&lA[wave * 16 + cl][ks * 32 + g * 8];
#pragma unroll
      for (int ct = 0; ct < 8; ++ct) {
        short8 b = *(const short8*)&lB[ct * 16 + cl][ks * 32 + g * 8];
        acc[ct] = __builtin_amdgcn_mfma_f32_16x16x32_bf16(a, b, acc[ct], 0, 0, 0);
      }
    }
  }
  __syncthreads();

  float bcol[8], gcol[8], ecol[8];
#pragma unroll
  for (int ct = 0; ct < 8; ++ct) {
    int c = ct * 16 + cl;
    bcol[ct] = bias[c]; gcol[ct] = gam[c]; ecol[ct] = bet[c];
  }
  float v[8][4];
  float s1[4] = {0.f, 0.f, 0.f, 0.f}, s2[4] = {0.f, 0.f, 0.f, 0.f};
#pragma unroll
  for (int ct = 0; ct < 8; ++ct)
#pragma unroll
    for (int r = 0; r < 4; ++r) {
      float t = acc[ct][r] + bcol[ct];
      v[ct][r] = t;
      s1[r] += t; s2[r] += t * t;
    }
#pragma unroll
  for (int m = 1; m <= 8; m <<= 1)
#pragma unroll
    for (int r = 0; r < 4; ++r) { s1[r] += __shfl_xor(s1[r], m); s2[r] += __shfl_xor(s2[r], m); }

#pragma unroll
  for (int r = 0; r < 4; ++r) {
    float mean = s1[r] * (1.f / 128.f);
    float var = s2[r] * (1.f / 128.f) - mean * mean;
    float rstd = rsqrtf(var + EPSV);
    int grow = rowBase + wave * 16 + g * 4 + r;
    if (grow < nN) {
      float o8v[8];
      float rmin = 1e30f, rmax = -1e30f;
#pragma unroll
      for (int ct = 0; ct < 8; ++ct) {
        int c = ct * 16 + cl;
        float o = fmaxf((v[ct][r] - mean) * rstd * gcol[ct] + ecol[ct], 0.f)
                  + b2f(hin16[(size_t)grow * 128 + c]);
        o8v[ct] = o;
        rmin = fminf(rmin, o); rmax = fmaxf(rmax, o);
        hout16[(size_t)grow * 128 + c] = f2b(o);
      }
      if (quant) {
#pragma unroll
        for (int m = 1; m <= 8; m <<= 1) {
          rmin = fminf(rmin, __shfl_xor(rmin, m));
          rmax = fmaxf(rmax, __shfl_xor(rmax, m));
        }
        float scale = (rmax - rmin) * (1.f / 255.f);
        float invq = (rmax > rmin) ? 255.f / (rmax - rmin) : 0.f;
#pragma unroll
        for (int ct = 0; ct < 8; ++ct) {
          int c = ct * 16 + cl;
          hout8[(size_t)grow * 128 + c] = (unsigned char)(int)rintf((o8v[ct] - rmin) * invq);
        }
        if (cl == 0) hmeta_o[grow] = make_float2(scale, rmin);
      }
    }
  }
}

// ---------------------------------------------------------------- GAT GEMM (MFMA) + logits
__global__ __launch_bounds__(256)
void k_gatgemm(const unsigned short* __restrict__ h16, const unsigned short* __restrict__ WgT,
               const float* __restrict__ atts, const float* __restrict__ attd,
               unsigned char* __restrict__ G8, float2* __restrict__ Gmeta,
               float* __restrict__ as_, float* __restrict__ ad_, int nN) {
  __shared__ unsigned short lA[64][136];
  __shared__ unsigned short lB[128][136];
  int tid = threadIdx.x;
  int wave = tid >> 6, lane = tid & 63;
  int cl = lane & 15, g = lane >> 4;
  int rowBase = blockIdx.x * 64;
  int y = blockIdx.y;
  f32x4 acc[8];
#pragma unroll
  for (int ct = 0; ct < 8; ++ct) acc[ct] = (f32x4){0.f, 0.f, 0.f, 0.f};

  int ar = tid >> 2, ap = (tid & 3) * 32;
  int br = tid >> 1, bp = (tid & 1) * 64;
  {
    int grow = rowBase + ar;
    if (grow < nN) {
      const unsigned short* sp = h16 + (size_t)grow * 128 + ap;
#pragma unroll
      for (int u = 0; u < 4; ++u)
        *(short8*)&lA[ar][ap + u * 8] = *(const short8*)(sp + u * 8);
    } else {
      short8 z = {0, 0, 0, 0, 0, 0, 0, 0};
#pragma unroll
      for (int u = 0; u < 4; ++u) *(short8*)&lA[ar][ap + u * 8] = z;
    }
    const unsigned short* bsp = WgT + (size_t)(y * 128 + br) * 128 + bp;
#pragma unroll
    for (int u = 0; u < 8; ++u)
      *(short8*)&lB[br][bp + u * 8] = *(const short8*)(bsp + u * 8);
  }
  __syncthreads();
#pragma unroll
  for (int ks = 0; ks < 4; ++ks) {
    short8 a = *(const short8*)&lA[wave * 16 + cl][ks * 32 + g * 8];
#pragma unroll
    for (int ct = 0; ct < 8; ++ct) {
      short8 b = *(const short8*)&lB[ct * 16 + cl][ks * 32 + g * 8];
      acc[ct] = __builtin_amdgcn_mfma_f32_16x16x32_bf16(a, b, acc[ct], 0, 0, 0);
    }
  }

  float atr[8], adr[8];
#pragma unroll
  for (int ct = 0; ct < 8; ++ct) {
    int h = y * 2 + (ct >> 2);
    int w = (ct & 3) * 16 + cl;
    atr[ct] = atts[h * 64 + w];
    adr[ct] = attd[h * 64 + w];
  }
  float ps[2][4], pd[2][4];
#pragma unroll
  for (int hh = 0; hh < 2; ++hh)
#pragma unroll
    for (int r = 0; r < 4; ++r) { ps[hh][r] = 0.f; pd[hh][r] = 0.f; }

#pragma unroll
  for (int r = 0; r < 4; ++r) {
    int grow = rowBase + wave * 16 + g * 4 + r;
    float rmin = 1e30f, rmax = -1e30f;
#pragma unroll
    for (int ct = 0; ct < 8; ++ct) {
      rmin = fminf(rmin, acc[ct][r]); rmax = fmaxf(rmax, acc[ct][r]);
    }
#pragma unroll
    for (int m = 1; m <= 8; m <<= 1) {
      rmin = fminf(rmin, __shfl_xor(rmin, m));
      rmax = fmaxf(rmax, __shfl_xor(rmax, m));
    }
    float scale = (rmax - rmin) * (1.f / 255.f);
    float invq = (rmax > rmin) ? 255.f / (rmax - rmin) : 0.f;
    if (grow < nN) {
      unsigned char* op = G8 + (size_t)grow * 256 + y * 128 + cl;
#pragma unroll
      for (int ct = 0; ct < 8; ++ct)
        op[ct * 16] = (unsigned char)(int)rintf((acc[ct][r] - rmin) * invq);
      if (cl == 0) Gmeta[grow * 2 + y] = make_float2(scale, rmin);
    }
#pragma unroll
    for (int ct = 0; ct < 8; ++ct) {
      ps[ct >> 2][r] = fmaf(acc[ct][r], atr[ct], ps[ct >> 2][r]);
      pd[ct >> 2][r] = fmaf(acc[ct][r], adr[ct], pd[ct >> 2][r]);
    }
  }
#pragma unroll
  for (int m = 1; m <= 8; m <<= 1)
#pragma unroll
    for (int hh = 0; hh < 2; ++hh)
#pragma unroll
      for (int r = 0; r < 4; ++r) {
        ps[hh][r] += __shfl_xor(ps[hh][r], m);
        pd[hh][r] += __shfl_xor(pd[hh][r], m);
      }
  if (cl == 0) {
#pragma unroll
    for (int r = 0; r < 4; ++r) {
      int grow = rowBase + wave * 16 + g * 4 + r;
      if (grow < nN) {
#pragma unroll
        for (int hh = 0; hh < 2; ++hh) {
          as_[grow * 4 + y * 2 + hh] = ps[hh][r];
          ad_[grow * 4 + y * 2 + hh] = pd[hh][r];
        }
      }
    }
  }
}

// ---------------------------------------------------------------- fused GAT gather + LN (uint8 G)
// 64 lanes/NODE: 32 payload-lanes (8 feats each) x 2 edge-slots (lane bit 5); 2 banks/slot
__global__ void k_gat(const unsigned char* __restrict__ G8, const float2* __restrict__ Gmeta,
                      const int* __restrict__ rowptr, const int* __restrict__ cnt,
                      const int* __restrict__ eSrc,
                      const float* __restrict__ as_, const float* __restrict__ ad_,
                      const float* __restrict__ bg, const float* __restrict__ g3,
                      const float* __restrict__ be3, float* __restrict__ out, int nN) {
  int t = blockIdx.x * 256 + threadIdx.x;
  int n = t >> 6;
  if (n >= nN) return;
  int lane = t & 63;
  int sub = lane & 31;
  int slot = lane >> 5;  // 0/1
  int h = sub >> 3;
  int yy = sub >> 4;
  int fo = sub * 8;
  float adn = ad_[n * 4 + h];

  float a0[8], a1[8];
#pragma unroll
  for (int j = 0; j < 8; ++j) { a0[j] = 0.f; a1[j] = 0.f; }
  float m0 = 0.f, m1 = 0.f, d0 = 0.f, d1 = 0.f;

  if (slot == 0) {  // self loop -> bank 0 of slot 0
    float e0 = as_[n * 4 + h] + adn;
    e0 = fmaxf(e0, 0.2f * e0);
    float w = __expf(e0);
    float2 mts = Gmeta[n * 2 + yy];
    uint2 p = *(const uint2*)(G8 + (size_t)n * 256 + fo);
    float ws = w * mts.x;
#pragma unroll
    for (int j = 0; j < 4; ++j) {
      a0[j] = ws * ub(p.x, j);
      a0[j + 4] = ws * ub(p.y, j);
    }
    m0 = w * mts.y;
    d0 = w;
  }

  int beg = rowptr[n], c = cnt[n];
  int i = slot;
  for (; i + 2 < c; i += 4) {  // edges i and i+2
    int s0 = eSrc[beg + i], s1i = eSrc[beg + i + 2];
    float ev0 = as_[s0 * 4 + h] + adn;
    float ev1 = as_[s1i * 4 + h] + adn;
    ev0 = fmaxf(ev0, 0.2f * ev0); ev1 = fmaxf(ev1, 0.2f * ev1);
    float w0 = __expf(ev0), w1 = __expf(ev1);
    float2 t0 = Gmeta[s0 * 2 + yy], t1 = Gmeta[s1i * 2 + yy];
    uint2 p0 = *(const uint2*)(G8 + (size_t)s0 * 256 + fo);
    uint2 p1 = *(const uint2*)(G8 + (size_t)s1i * 256 + fo);
    float ws0 = w0 * t0.x, ws1 = w1 * t1.x;
#pragma unroll
    for (int j = 0; j < 4; ++j) {
      a0[j] = fmaf(ws0, ub(p0.x, j), a0[j]);
      a1[j] = fmaf(ws1, ub(p1.x, j), a1[j]);
      a0[j + 4] = fmaf(ws0, ub(p0.y, j), a0[j + 4]);
      a1[j + 4] = fmaf(ws1, ub(p1.y, j), a1[j + 4]);
    }
    m0 = fmaf(w0, t0.y, m0); m1 = fmaf(w1, t1.y, m1);
    d0 += w0; d1 += w1;
  }
  for (; i < c; i += 2) {
    int s = eSrc[beg + i];
    float ev = as_[s * 4 + h] + adn;
    ev = fmaxf(ev, 0.2f * ev);
    float w = __expf(ev);
    float2 tm = Gmeta[s * 2 + yy];
    uint2 p = *(const uint2*)(G8 + (size_t)s * 256 + fo);
    float wsx = w * tm.x;
#pragma unroll
    for (int j = 0; j < 4; ++j) {
      a0[j] = fmaf(wsx, ub(p.x, j), a0[j]);
      a0[j + 4] = fmaf(wsx, ub(p.y, j), a0[j + 4]);
    }
    m0 = fmaf(w, tm.y, m0);
    d0 += w;
  }

  float den = d0 + d1;
  float mm = m0 + m1;
  float a[8];
#pragma unroll
  for (int j = 0; j < 8; ++j) a[j] = a0[j] + a1[j];
  // merge the two edge-slots (lane bit 5)
#pragma unroll
  for (int j = 0; j < 8; ++j) a[j] += __shfl_xor(a[j], 32);
  den += __shfl_xor(den, 32);
  mm += __shfl_xor(mm, 32);

  float inv = 1.f / den;
#pragma unroll
  for (int j = 0; j < 8; ++j) a[j] = (a[j] + mm) * inv;

  // head-mean over lane bits 3,4
#pragma unroll
  for (int j = 0; j < 8; ++j) {
    a[j] += __shfl_xor(a[j], 8);
    a[j] += __shfl_xor(a[j], 16);
  }
  int fb = (sub & 7) * 8;
  float v[8];
  float s1 = 0.f, s2 = 0.f;
#pragma unroll
  for (int j = 0; j < 8; ++j) {
    v[j] = a[j] * 0.25f + bg[fb + j];
    s1 += v[j]; s2 += v[j] * v[j];
  }
  // LN over 64 feats: reduce across lane bits 0-2
#pragma unroll
  for (int m = 1; m <= 4; m <<= 1) { s1 += __shfl_xor(s1, m); s2 += __shfl_xor(s2, m); }
  float mean = s1 * (1.f / 64.f);
  float var = s2 * (1.f / 64.f) - mean * mean;
  float rstd = rsqrtf(var + EPSV);
  if (lane < 8) {
    float* o = out + (size_t)n * 64 + fb;
    float4 o1, o2;
    o1.x = (v[0] - mean) * rstd * g3[fb + 0] + be3[fb + 0];
    o1.y = (v[1] - mean) * rstd * g3[fb + 1] + be3[fb + 1];
    o1.z = (v[2] - mean) * rstd * g3[fb + 2] + be3[fb + 2];
    o1.w = (v[3] - mean) * rstd * g3[fb + 3] + be3[fb + 3];
    o2.x = (v[4] - mean) * rstd * g3[fb + 4] + be3[fb + 4];
    o2.y = (v[5] - mean) * rstd * g3[fb + 5] + be3[fb + 5];
    o2.z = (v[6] - mean) * rstd * g3[fb + 6] + be3[fb + 6];
    o2.w = (v[7] - mean) * rstd * g3[fb + 7] + be3[fb + 7];
    *(float4*)o = o1;
    *(float4*)(o + 4) = o2;
  }
}

// ================================================================ launch
extern "C" void kernel_launch(void* const* d_in, const int* in_sizes, int n_in,
                              void* d_out, int out_size, void* d_ws, size_t ws_size,
                              hipStream_t stream) {
  const float* x    = (const float*)d_in[0];
  const int*   edge = (const int*)d_in[1];
  const float* W_in = (const float*)d_in[2];
  const float* b_in = (const float*)d_in[3];
  const float* W1_l = (const float*)d_in[4];
  const float* b1   = (const float*)d_in[5];
  const float* W1_r = (const float*)d_in[6];
  const float* g1   = (const float*)d_in[7];
  const float* be1  = (const float*)d_in[8];
  const float* W2_l = (const float*)d_in[9];
  const float* b2   = (const float*)d_in[10];
  const float* W2_r = (const float*)d_in[11];
  const float* g2   = (const float*)d_in[12];
  const float* be2  = (const float*)d_in[13];
  const float* W_g  = (const float*)d_in[14];
  const float* atts = (const float*)d_in[15];
  const float* attd = (const float*)d_in[16];
  const float* b_g  = (const float*)d_in[17];
  const float* g3   = (const float*)d_in[18];
  const float* be3  = (const float*)d_in[19];

  const int nN = in_sizes[0] / 14;
  const int E_ = in_sizes[1] / 2;
  const int* src = edge;
  const int* dst = edge + E_;

  char* W = (char*)d_ws;
  unsigned short* hA16  = (unsigned short*)W; W += (size_t)nN * 128 * 2;
  unsigned short* hB16  = (unsigned short*)W; W += (size_t)nN * 128 * 2;
  unsigned short* agg16 = (unsigned short*)W; W += (size_t)nN * 128 * 2;
  unsigned short* WlT1  = (unsigned short*)W; W += 16384 * 2;
  unsigned short* WrT1  = (unsigned short*)W; W += 16384 * 2;
  unsigned short* WlT2  = (unsigned short*)W; W += 16384 * 2;
  unsigned short* WrT2  = (unsigned short*)W; W += 16384 * 2;
  unsigned short* WgT   = (unsigned short*)W; W += 32768 * 2;
  float* AS_ = (float*)W;                W += (size_t)nN * 4 * 4;
  float* AD_ = (float*)W;                W += (size_t)nN * 4 * 4;
  float2* metaA = (float2*)W;            W += (size_t)nN * 8;
  float2* metaB = (float2*)W;            W += (size_t)nN * 8;
  float2* Gmeta = (float2*)W;            W += (size_t)nN * 2 * 8;
  int* cntI   = (int*)W;                 W += (size_t)nN * 4;
  int* rowptr = (int*)W;                 W += (size_t)nN * 4;
  int* cursor = (int*)W;                 W += (size_t)nN * 4;
  int* incl   = (int*)W;                 W += (size_t)nN * 4;
  int* bsum   = (int*)W;                 W += 1024 * 4;
  int* eSrc   = (int*)W;                 W += (size_t)E_ * 4;
  unsigned char* h8A = (unsigned char*)W; W += (size_t)nN * 128;
  unsigned char* h8B = (unsigned char*)W; W += (size_t)nN * 128;
  unsigned char* G8  = (unsigned char*)W; W += (size_t)nN * 256;

  const int SB = (nN + 255) / 256;  // 196 for N=50000 (must be <=256)
  const int NB = (nN + 63) / 64;

  // weight prep + zero cnt/cursor (independent of graph; all layers upfront)
  k_prep_all<<<384, 256, 0, stream>>>(W1_l, W1_r, W2_l, W2_r, W_g, WlT1, WrT1, WlT2, WrT2,
                                      WgT, cntI, cursor, nN);

  // CSR by dst
  k_count_int<<<(E_ + 255) / 256, 256, 0, stream>>>(dst, cntI, E_);
  k_scan1<<<SB, 256, 0, stream>>>(cntI, incl, bsum, nN);
  k_scan2<<<1, 256, 0, stream>>>(bsum, SB);
  k_scan3<<<SB, 256, 0, stream>>>(incl, bsum, cntI, rowptr, nN);
  k_fill<<<(E_ + 255) / 256, 256, 0, stream>>>(src, dst, rowptr, cursor, eSrc, E_);

  // input projection
  k_proj<<<(nN * 64 + 255) / 256, 256, 0, stream>>>(x, W_in, b_in, hA16, h8A, metaA, nN);

  // SAGE layer 1: hA -> hB
  k_sage_gather8<<<(nN * 64 + 255) / 256, 256, 0, stream>>>(h8A, metaA, rowptr, cntI, eSrc, agg16, nN);
  k_sage_mfma<<<NB, 256, 0, stream>>>(agg16, hA16, WlT1, WrT1, b1, g1, be1, hB16, h8B, metaB, 1, nN);

  // SAGE layer 2: hB -> hA
  k_sage_gather8<<<(nN * 64 + 255) / 256, 256, 0, stream>>>(h8B, metaB, rowptr, cntI, eSrc, agg16, nN);
  k_sage_mfma<<<NB, 256, 0, stream>>>(agg16, hB16, WlT2, WrT2, b2, g2, be2, hA16, h8A, metaA, 0, nN);

  // GAT: hA16 -> G8(+meta,+logits) -> out
  k_gatgemm<<<dim3(NB, 2), 256, 0, stream>>>(hA16, WgT, atts, attd, G8, Gmeta, AS_, AD_, nN);
  k_gat<<<(nN * 64 + 255) / 256, 256, 0, stream>>>(G8, Gmeta, rowptr, cntI, eSrc, AS_, AD_, b_g, g3, be3, (float*)d_out, nN);
}